// Round 3
// baseline (539.408 us; speedup 1.0000x reference)
//
#include <hip/hip_runtime.h>
#include <hip/hip_bf16.h>
#include <math.h>

// out[b,f,h,w] = sum_c M[f,c] * x[b,c,h,w],  M = Qinv @ diag(exp(-2*T*|S|)) @ Q
// B=4, C=64, H=W=512.  Treated as GEMM: out[64, 1M] = M[64,64] @ x[64, 1M],
// via split-bf16 MFMA: out = Mh*xh + Mh*xl + Ml*xh (fp32 accum).

#define C_DIM 64
#define HW (512 * 512)   // 2^18

typedef __attribute__((ext_vector_type(8))) short short8;
typedef __attribute__((ext_vector_type(4))) float float4v;

__device__ inline unsigned short f32_to_bf16_rne(float f) {
    unsigned int u = __float_as_uint(f);
    unsigned int r = (u + 0x7fffu + ((u >> 16) & 1u)) >> 16;
    return (unsigned short)r;
}
__device__ inline float bf16_to_f32(unsigned short h) {
    return __uint_as_float(((unsigned int)h) << 16);
}

// ---- Kernel 1: M = Qinv @ diag(exp(-2T|S|)) @ Q, split into bf16 hi + residual ----
__global__ __launch_bounds__(256) void compute_M_kernel(
    const float* __restrict__ S, const float* __restrict__ Q,
    const float* __restrict__ Qinv, const int* __restrict__ Tp,
    unsigned short* __restrict__ Mh, unsigned short* __restrict__ Ml) {
    __shared__ float d[C_DIM];
    int tid = threadIdx.x;
    if (tid < C_DIM) {
        float t = (float)(*Tp);
        d[tid] = expf(-2.0f * t * fabsf(S[tid]));
    }
    __syncthreads();
    int gid = blockIdx.x * 256 + tid;   // 0..4095
    int f = gid >> 6;
    int k = gid & 63;
    float acc = 0.0f;
    #pragma unroll
    for (int c = 0; c < C_DIM; ++c) {
        acc = fmaf(Qinv[f * C_DIM + c] * d[c], Q[c * C_DIM + k], acc);
    }
    unsigned short h = f32_to_bf16_rne(acc);
    Mh[gid] = h;
    Ml[gid] = f32_to_bf16_rne(acc - bf16_to_f32(h));
}

// ---- Kernel 2: MFMA apply. Each wave: 16 pixels x all 64 output channels. ----
// mfma_f32_16x16x32_bf16 layouts (guide-verified):
//   A[m][k]: m = lane&15, k = (lane>>4)*8 + j   (j = element in short8)
//   B[k][n]: k = (lane>>4)*8 + j, n = lane&15
//   C/D:     row = (lane>>4)*4 + r, col = lane&15
__global__ __launch_bounds__(256) void apply_M_mfma(
    const float* __restrict__ x, const unsigned short* __restrict__ Mh,
    const unsigned short* __restrict__ Ml, float* __restrict__ out) {
    int lane = threadIdx.x & 63;
    int wid = (blockIdx.x * 256 + threadIdx.x) >> 6;   // global wave id, 0..65535
    int n  = lane & 15;
    int kg = lane >> 4;

    long long px0 = (long long)wid * 16;
    int b = (int)(px0 >> 18);          // px0 / HW
    int s = (int)(px0 & (HW - 1));     // px0 % HW  (multiple of 16)

    const float* xb = x   + (size_t)b * C_DIM * HW + s + n;
    float*       ob = out + (size_t)b * C_DIM * HW + s + n;

    // ---- load this lane's 16 x values (channels kt*32 + kg*8 + j) ----
    float xf[2][8];
    #pragma unroll
    for (int kt = 0; kt < 2; ++kt) {
        #pragma unroll
        for (int j = 0; j < 8; ++j) {
            int c = kt * 32 + kg * 8 + j;
            xf[kt][j] = xb[(size_t)c * HW];
        }
    }

    // ---- split to bf16 hi/lo B-fragments ----
    short8 Bh[2], Bl[2];
    #pragma unroll
    for (int kt = 0; kt < 2; ++kt) {
        #pragma unroll
        for (int j = 0; j < 8; ++j) {
            float v = xf[kt][j];
            unsigned short h = f32_to_bf16_rne(v);
            float rem = v - bf16_to_f32(h);
            Bh[kt][j] = (short)h;
            Bl[kt][j] = (short)f32_to_bf16_rne(rem);
        }
    }

    float4v acc[4];
    #pragma unroll
    for (int ft = 0; ft < 4; ++ft) acc[ft] = (float4v){0.f, 0.f, 0.f, 0.f};

    #pragma unroll
    for (int ft = 0; ft < 4; ++ft) {
        #pragma unroll
        for (int kt = 0; kt < 2; ++kt) {
            // A fragment: rows ft*16 + (lane&15), k = kt*32 + kg*8 + j (contiguous)
            size_t aoff = (size_t)(ft * 16 + n) * C_DIM + kt * 32 + kg * 8;
            short8 ah = *reinterpret_cast<const short8*>(Mh + aoff);
            short8 al = *reinterpret_cast<const short8*>(Ml + aoff);
            acc[ft] = __builtin_amdgcn_mfma_f32_16x16x32_bf16(ah, Bh[kt], acc[ft], 0, 0, 0);
            acc[ft] = __builtin_amdgcn_mfma_f32_16x16x32_bf16(ah, Bl[kt], acc[ft], 0, 0, 0);
            acc[ft] = __builtin_amdgcn_mfma_f32_16x16x32_bf16(al, Bh[kt], acc[ft], 0, 0, 0);
        }
    }

    // ---- store: f = ft*16 + kg*4 + r at pixel px0 + n ----
    #pragma unroll
    for (int ft = 0; ft < 4; ++ft) {
        #pragma unroll
        for (int r = 0; r < 4; ++r) {
            int f = ft * 16 + kg * 4 + r;
            ob[(size_t)f * HW] = acc[ft][r];
        }
    }
}

extern "C" void kernel_launch(void* const* d_in, const int* in_sizes, int n_in,
                              void* d_out, int out_size, void* d_ws, size_t ws_size,
                              hipStream_t stream) {
    const float* x    = (const float*)d_in[0];
    const float* S    = (const float*)d_in[1];
    const float* Q    = (const float*)d_in[2];
    const float* Qinv = (const float*)d_in[3];
    const int*   Tp   = (const int*)d_in[4];
    float* out = (float*)d_out;

    unsigned short* Mh = (unsigned short*)d_ws;            // 8 KB
    unsigned short* Ml = Mh + C_DIM * C_DIM;               // 8 KB

    compute_M_kernel<<<16, 256, 0, stream>>>(S, Q, Qinv, Tp, Mh, Ml);

    // 4*HW pixels, 16 px per wave, 4 waves per block -> 16384 blocks
    int total_waves = (4 * HW) / 16;
    apply_M_mfma<<<total_waves / 4, 256, 0, stream>>>(x, Mh, Ml, out);
}